// Round 1
// baseline (10.777 us; speedup 1.0000x reference)
//
#include <hip/hip_runtime.h>

// RelationLoss: loss = mean( ((x_j-x_i)^2 - (t_j-t_i)^2)^2 ) over [C, N, N]
// Collapsed to per-channel moments (see derivation in session notes):
//   Sa4  = 2N*S4x - 8*S3x*S1x + 6*S2x^2
//   Sb4  = 2N*S4t - 8*S3t*S1t + 6*S2t^2
//   Sab  = 2N*Sx2t2 - 4*Sx2t*S1t - 4*Sxt2*S1x + 2*S2x*S2t + 4*Sxt^2
//   channel = Sa4 - 2*Sab + Sb4 ;  loss = sum_c(channel) / (C*N*N)

#define C_CH 128
#define N_EL 1024
#define NS 12

__global__ __launch_bounds__(256) void relloss_stage1(
    const float* __restrict__ x, const float* __restrict__ t,
    double* __restrict__ ws) {
  const int c = blockIdx.x;
  const int tid = threadIdx.x;
  const float* __restrict__ xr = x + c * N_EL;
  const float* __restrict__ tr = t + c * N_EL;

  double s[NS];
#pragma unroll
  for (int k = 0; k < NS; ++k) s[k] = 0.0;

  for (int i = tid; i < N_EL; i += 256) {
    const double xv = (double)xr[i];
    const double tv = (double)tr[i];
    const double x2 = xv * xv, t2 = tv * tv;
    s[0] += xv;        // S1x
    s[1] += x2;        // S2x
    s[2] += x2 * xv;   // S3x
    s[3] += x2 * x2;   // S4x
    s[4] += tv;        // S1t
    s[5] += t2;        // S2t
    s[6] += t2 * tv;   // S3t
    s[7] += t2 * t2;   // S4t
    s[8] += xv * tv;   // Sxt
    s[9] += x2 * tv;   // Sx2t
    s[10] += xv * t2;  // Sxt2
    s[11] += x2 * t2;  // Sx2t2
  }

  // wave (64-lane) shuffle reduce
#pragma unroll
  for (int k = 0; k < NS; ++k) {
#pragma unroll
    for (int off = 32; off > 0; off >>= 1) s[k] += __shfl_down(s[k], off, 64);
  }

  __shared__ double lds[4][NS];
  const int wave = tid >> 6;
  const int lane = tid & 63;
  if (lane == 0) {
#pragma unroll
    for (int k = 0; k < NS; ++k) lds[wave][k] = s[k];
  }
  __syncthreads();

  if (tid == 0) {
    double r[NS];
#pragma unroll
    for (int k = 0; k < NS; ++k)
      r[k] = lds[0][k] + lds[1][k] + lds[2][k] + lds[3][k];
    const double Nn = (double)N_EL;
    const double termX = 2.0 * Nn * r[3] - 8.0 * r[2] * r[0] + 6.0 * r[1] * r[1];
    const double termT = 2.0 * Nn * r[7] - 8.0 * r[6] * r[4] + 6.0 * r[5] * r[5];
    const double cross = 2.0 * Nn * r[11] - 4.0 * r[9] * r[4] - 4.0 * r[10] * r[0] +
                         2.0 * r[1] * r[5] + 4.0 * r[8] * r[8];
    ws[c] = termX - 2.0 * cross + termT;
  }
}

__global__ __launch_bounds__(128) void relloss_stage2(
    const double* __restrict__ ws, float* __restrict__ out) {
  const int tid = threadIdx.x;
  double v = ws[tid];
#pragma unroll
  for (int off = 32; off > 0; off >>= 1) v += __shfl_down(v, off, 64);
  __shared__ double lds[2];
  if ((tid & 63) == 0) lds[tid >> 6] = v;
  __syncthreads();
  if (tid == 0) {
    const double total = lds[0] + lds[1];
    // LOSS_WEIGHT = 1.0
    out[0] = (float)(total / ((double)C_CH * (double)N_EL * (double)N_EL));
  }
}

extern "C" void kernel_launch(void* const* d_in, const int* in_sizes, int n_in,
                              void* d_out, int out_size, void* d_ws, size_t ws_size,
                              hipStream_t stream) {
  const float* x = (const float*)d_in[0];
  const float* t = (const float*)d_in[1];
  double* ws = (double*)d_ws;
  float* out = (float*)d_out;

  relloss_stage1<<<C_CH, 256, 0, stream>>>(x, t, ws);
  relloss_stage2<<<1, 128, 0, stream>>>(ws, out);
}